// Round 2
// 63.829 us; speedup vs baseline: 1.0592x; 1.0592x over previous
//
#include <hip/hip_runtime.h>

// Span masking — bit-exact JAX threefry2x32 stream (verified R5-R16).
// R17: cold-memory mitigation (parallel table/token loads first; kTab=1024).
// R18: serial-path cuts. (a) Replace both 6-step __shfl_xor wave reductions
// (batch count + binary-search probes) with the classic GCN DPP chain
// (row_shr 1/2/4/8 + row_bcast 15/31 + readlane 63): ~200cy of dependent
// ds_bpermute -> ~40cy of VALU, on the critical path ~16x per row; sum lands
// in an SGPR so cur/target flow stays wave-uniform. (b) Un-pin the prelude
// draw loop (#pragma unroll 1 -> full unroll): 4 independent ~60-deep
// threefry+log chains interleave instead of serializing (walk waves have
// 1 wave/SIMD -> no TLP to hide dependent latency otherwise).
// R18b: identical resubmit (R18 bench was an infra failure, no data).
//
// Stream (jax_threefry_partitionable=True):
//   split(key,n): keys[i] = (y0,y1) of tf(key,(0,i))
//   random_bits(key,32,(128,))[r] = y0^y1 of tf(key,(0,r))
//   _randint: (k1,k2)=split(key,2); span=2^13 -> start = bits(k2)[r] & 8191
//   _uniform: bits(key) directly
//   chain: key_{t+1}=tf(key_t,(0,0)); k2_t=tf(tf(key_t,(0,1)),(0,1));
//          kl_t=tf(key_t,(0,2)); key_0=(0,42)

static constexpr int kB = 128;
static constexpr int kS = 8192;
static constexpr int kWords = kS / 32;   // 256
static constexpr int kMaskTok = 50256;
static constexpr int kBatch = 64;
static constexpr int kTab = 1024;        // precomputed iterations (need ~704)
static constexpr int kTabBatches = kTab / kBatch;  // 16
static constexpr int kMaxBatches = 256;  // incl. fallback region
static constexpr int kJ = kTab / 256;    // 4 draws per thread

// ---------------- compile-time threefry ----------------
struct KeyPair { unsigned a, b; };

constexpr unsigned rotl_c(unsigned x, int r) {
  return (x << r) | (x >> (32 - r));
}

constexpr KeyPair tf_c(unsigned k0, unsigned k1, unsigned x0, unsigned x1) {
  unsigned ks[3] = {k0, k1, k0 ^ k1 ^ 0x1BD11BDAu};
  unsigned v0 = x0 + ks[0], v1 = x1 + ks[1];
  const int RA[4] = {13, 15, 26, 6};
  const int RB[4] = {17, 29, 16, 24};
  for (int g = 0; g < 5; ++g) {
    const int* r = (g & 1) ? RB : RA;
    for (int i = 0; i < 4; ++i) { v0 += v1; v1 = rotl_c(v1, r[i]); v1 ^= v0; }
    v0 += ks[(g + 1) % 3];
    v1 += ks[(g + 2) % 3] + (unsigned)(g + 1);
  }
  return {v0, v1};
}

struct alignas(16) Entry { unsigned k2a, k2b, kla, klb; };
static constexpr int kChunk = 256;
struct Chunk { Entry e[kChunk]; KeyPair end; };

constexpr Chunk make_chunk(KeyPair s) {
  Chunk c{};
  KeyPair key = s;
  for (int i = 0; i < kChunk; ++i) {
    KeyPair ks = tf_c(key.a, key.b, 0u, 1u);   // subkey 1 of split(key,3)
    KeyPair kl = tf_c(key.a, key.b, 0u, 2u);   // subkey 2
    KeyPair k2 = tf_c(ks.a, ks.b, 0u, 1u);     // split(ks,2)[1]
    c.e[i] = Entry{k2.a, k2.b, kl.a, kl.b};
    key = tf_c(key.a, key.b, 0u, 0u);          // chain link
  }
  c.end = key;
  return c;
}

constexpr Chunk g_c0 = make_chunk(KeyPair{0u, 42u});
constexpr Chunk g_c1 = make_chunk(g_c0.end);
constexpr Chunk g_c2 = make_chunk(g_c1.end);
constexpr Chunk g_c3 = make_chunk(g_c2.end);

struct TabAll { Entry e[kTab]; };
constexpr TabAll make_all() {
  TabAll t{};
  const Chunk* cs[4] = {&g_c0, &g_c1, &g_c2, &g_c3};
  for (int c = 0; c < 4; ++c)
    for (int i = 0; i < kChunk; ++i)
      t.e[c * kChunk + i] = cs[c]->e[i];
  return t;
}

__constant__ TabAll g_tab = make_all();
__constant__ KeyPair g_chain_end = g_c3.end;   // key state at iteration kTab

// ---------------- device threefry (verified R5-R16) ----------------
__device__ __forceinline__ void tf2x32(unsigned k0, unsigned k1,
                                       unsigned x0, unsigned x1,
                                       unsigned& y0, unsigned& y1) {
  const unsigned ks0 = k0, ks1 = k1, ks2 = k0 ^ k1 ^ 0x1BD11BDAu;
  unsigned v0 = x0 + ks0;
  unsigned v1 = x1 + ks1;
#define TF_R(r) do { v0 += v1; v1 = (v1 << (r)) | (v1 >> (32 - (r))); v1 ^= v0; } while (0)
  TF_R(13); TF_R(15); TF_R(26); TF_R(6);
  v0 += ks1; v1 += ks2 + 1u;
  TF_R(17); TF_R(29); TF_R(16); TF_R(24);
  v0 += ks2; v1 += ks0 + 2u;
  TF_R(13); TF_R(15); TF_R(26); TF_R(6);
  v0 += ks0; v1 += ks1 + 3u;
  TF_R(17); TF_R(29); TF_R(16); TF_R(24);
  v0 += ks1; v1 += ks2 + 4u;
  TF_R(13); TF_R(15); TF_R(26); TF_R(6);
  v0 += ks2; v1 += ks0 + 5u;
#undef TF_R
  y0 = v0; y1 = v1;
}

// Full verified draw path: (k2,kl,r) -> packed start|len<<16 (R13, absmax 0).
__device__ __forceinline__ unsigned draw_pack(unsigned k2A, unsigned k2B,
                                              unsigned klA, unsigned klB,
                                              int r) {
  unsigned d0, d1, e0, e1;
  tf2x32(k2A, k2B, 0u, (unsigned)r, d0, d1);  // start bits
  tf2x32(klA, klB, 0u, (unsigned)r, e0, e1);  // uniform bits
  const int start = (int)((d0 ^ d1) & 8191u);
  const unsigned ubits = e0 ^ e1;
  float f = __uint_as_float((ubits >> 9) | 0x3F800000u) - 1.0f;  // exact
  float val = __fadd_rn(__fmul_rn(f, (1.0f - 1e-7f)), 1e-7f);    // no FMA
  float u = fmaxf(1e-7f, val);
  float lf = (float)log((double)u);   // correctly-rounded f32 log
  float q = __fdiv_rn(lf, -0.40546512603759765625f);
  int geo = (int)floorf(q) + 1;       // 1..40
  int len = min(geo, kS - start);     // 1..40
  return (unsigned)start | ((unsigned)len << 16);
}

// Span's bit pattern within absolute word w, given [start,end).
__device__ __forceinline__ unsigned span_bits(int start, int end, int w) {
  int lo = max(start - (w << 5), 0);
  int hi = min(end - (w << 5), 32);
  return (hi >= 32 ? 0xFFFFFFFFu : ((1u << hi) - 1u)) & (0xFFFFFFFFu << lo);
}

// R18: wave64 sum via GCN DPP chain. row_shr with bound_ctrl shifts in 0;
// after 1/2/4/8 each row-of-16's lane 15/31/47/63 holds its row sum;
// row_bcast:15 then row_bcast:31 fold rows; lane 63 holds the total.
// Returns a wave-uniform value on all lanes (via readlane -> SGPR).
__device__ __forceinline__ int wave_sum64(int x) {
  x += __builtin_amdgcn_update_dpp(0, x, 0x111, 0xF, 0xF, true);  // row_shr:1
  x += __builtin_amdgcn_update_dpp(0, x, 0x112, 0xF, 0xF, true);  // row_shr:2
  x += __builtin_amdgcn_update_dpp(0, x, 0x114, 0xF, 0xF, true);  // row_shr:4
  x += __builtin_amdgcn_update_dpp(0, x, 0x118, 0xF, 0xF, true);  // row_shr:8
  x += __builtin_amdgcn_update_dpp(0, x, 0x142, 0xF, 0xF, true);  // row_bcast:15
  x += __builtin_amdgcn_update_dpp(0, x, 0x143, 0xF, 0xF, true);  // row_bcast:31
  return __builtin_amdgcn_readlane(x, 63);
}

__global__ __launch_bounds__(256)
void span_mask_kernel(const int* __restrict__ x0tok,
                      const float* __restrict__ mask_prob,
                      int* __restrict__ out) {
  const int r = blockIdx.x;
  const int tid = threadIdx.x;

  __shared__ __align__(16) unsigned maskw[kWords];
  __shared__ unsigned dtab[kTab];   // this row's draws, start|len<<16

  // ---- cold loads issued FIRST (L2/L3 swept by the 256MB poison fill):
  // mask_prob scalar, all table entries (parallel), epilogue tokens.
  const float mp = mask_prob[r];
  Entry ent[kJ];
#pragma unroll
  for (int j = 0; j < kJ; ++j) ent[j] = g_tab.e[j * 256 + tid];
  const int base4 = r * (kS / 4);   // 2048 int4 per row; 8 per thread
  int4 tok[8];
#pragma unroll
  for (int k = 0; k < 8; ++k)
    tok[k] = ((const int4*)x0tok)[base4 + k * 256 + tid];

  for (int i = tid; i < kWords; i += 256) maskw[i] = 0u;

  // ---- prelude: 1024 draws, 4/thread, fully unrolled so the 4 independent
  // threefry+log dependency chains interleave (R18; loads already in flight)
#pragma unroll
  for (int j = 0; j < kJ; ++j) {
    const int t = j * 256 + tid;
    dtab[t] = draw_pack(ent[j].k2a, ent[j].k2b, ent[j].kla, ent[j].klb, r);
  }
  __syncthreads();

  // ---- walk: wave 0 only (verified batch apply; binary-search crossing) ---
  if (tid < 64) {
    const int lane = tid;
    const int target = (int)floorf(mp * 8192.0f);  // *2^13 exact

    int cur = 0;
    unsigned fb0 = 0u, fb1 = 0u;   // fallback chain state (iters >= kTab)
    bool fb_init = false;
    unsigned nxt = dtab[lane];     // batch-0 draw, prefetched

    for (int b = 0; b < kMaxBatches; ++b) {
      unsigned pkc;
      if (b < kTabBatches) {
        pkc = nxt;
        if (b + 1 < kTabBatches) nxt = dtab[(b + 1) * 64 + lane];
      } else {
        // tier-3 fallback: runtime walk from baked end-state (verified R12)
        if (!fb_init) { fb0 = g_chain_end.a; fb1 = g_chain_end.b; fb_init = true; }
        unsigned mk0 = 0u, mk1 = 0u;
#pragma unroll 1
        for (int t = 0; t < kBatch; ++t) {
          const bool sel = (lane == t);
          mk0 = sel ? fb0 : mk0;
          mk1 = sel ? fb1 : mk1;
          unsigned n0, n1;
          tf2x32(fb0, fb1, 0u, 0u, n0, n1);
          fb0 = n0; fb1 = n1;
        }
        unsigned ksA, ksB, klA, klB, k2A, k2B;
        tf2x32(mk0, mk1, 0u, 1u, ksA, ksB);
        tf2x32(mk0, mk1, 0u, 2u, klA, klB);
        tf2x32(ksA, ksB, 0u, 1u, k2A, k2B);
        pkc = draw_pack(k2A, k2B, klA, klB, r);
      }
      const int start = (int)(pkc & 8191u);
      const int end = start + (int)(pkc >> 16);
      const int w0 = start >> 5, w1 = (end - 1) >> 5;  // <=3 words (len<=40)

      // optimistic apply; exact count from atomic returns (single wave:
      // DS ops execute in issue order; no barriers needed)
      uint4 pre = *(const uint4*)&maskw[4 * lane];  // pre-batch snapshot
      int d = 0;
#pragma unroll
      for (int k = 0; k < 3; ++k) {
        int w = w0 + k;
        if (w <= w1) {
          unsigned bits = span_bits(start, end, w);
          unsigned old = atomicOr(&maskw[w], bits);
          d += __popc(bits & ~old);   // Σ over ops = |new union bits| exact
        }
      }
      const int newcur = cur + wave_sum64(d);   // R18: DPP reduce, uniform

      if (newcur < target) { cur = newcur; continue; }  // batch fully valid

      // ---- crossing batch: binary search for smallest n, count(n)>=target.
      // Invariant: count(lo) < target <= count(hi); count(0)=cur < target.
      int lo = 0, hi = 64;
      while (hi - lo > 1) {   // 6 probes
        const int mid = (lo + hi) >> 1;
        *(uint4*)&maskw[4 * lane] = pre;   // restore snapshot
        int dm = 0;
        if (lane < mid) {
#pragma unroll
          for (int k = 0; k < 3; ++k) {
            int w = w0 + k;
            if (w <= w1) {
              unsigned bits = span_bits(start, end, w);
              unsigned old = atomicOr(&maskw[w], bits);
              dm += __popc(bits & ~old);
            }
          }
        }
        const int dmsum = wave_sum64(dm);   // R18: DPP reduce, uniform
        if (cur + dmsum < target) lo = mid; else hi = mid;
      }
      // final state: prior mask ∪ spans_{0..hi-1}
      *(uint4*)&maskw[4 * lane] = pre;
      if (lane < hi) {
#pragma unroll
        for (int k = 0; k < 3; ++k) {
          int w = w0 + k;
          if (w <= w1) atomicOr(&maskw[w], span_bits(start, end, w));
        }
      }
      break;  // row done
    }
  }

  __syncthreads();  // waves 1-3 waited here during the walk

  // ---- epilogue: 4-wave int4 stores (tok[] loaded at kernel start) --------
#pragma unroll
  for (int k = 0; k < 8; ++k) {
    const int i = k * 256 + tid;
    unsigned nib = maskw[i >> 3] >> ((i & 7) * 4);
    int4 xm, mm;
    mm.x = (int)(nib & 1u);        xm.x = mm.x ? kMaskTok : tok[k].x;
    mm.y = (int)((nib >> 1) & 1u); xm.y = mm.y ? kMaskTok : tok[k].y;
    mm.z = (int)((nib >> 2) & 1u); xm.z = mm.z ? kMaskTok : tok[k].z;
    mm.w = (int)((nib >> 3) & 1u); xm.w = mm.w ? kMaskTok : tok[k].w;
    ((int4*)out)[base4 + i] = xm;
    ((int4*)out)[kB * (kS / 4) + base4 + i] = mm;
  }
}

extern "C" void kernel_launch(void* const* d_in, const int* in_sizes, int n_in,
                              void* d_out, int out_size, void* d_ws, size_t ws_size,
                              hipStream_t stream) {
  const int* x0 = (const int*)d_in[0];
  const float* mp = (const float*)d_in[1];
  int* out = (int*)d_out;
  hipLaunchKernelGGL(span_mask_kernel, dim3(kB), dim3(256), 0, stream,
                     x0, mp, out);
}

// Round 3
// 63.604 us; speedup vs baseline: 1.0630x; 1.0035x over previous
//
#include <hip/hip_runtime.h>

// Span masking — bit-exact JAX threefry2x32 stream (verified R5-R16).
// R17: cold-memory mitigation (parallel table/token loads first).
// R18: DPP wave reductions (row_shr/row_bcast chain) + prelude unroll.
//      Measured 67.6 -> 63.8 us, absmax 0.
// R19: (a) 2 blocks per row (grid 256 = all CUs). Each pair-block duplicates
// the cheap prelude+walk (deterministic -> identical mask; parallel duplicate,
// wall time unchanged) but loads/stores only HALF the row's tokens: the
// 8MB epilogue store was running on 128 of 256 CUs (~3 TB/s per-CU cap);
// doubling grid doubles epilogue BW. tok[] 8->4 int4 (-16 VGPR).
// (b) kTab 1024->768: worst row needs ~704 draws (deterministic fixed-key
// inputs; crossing ~batch 11); 64-draw margin + unconditional tier-3
// fallback (re-anchored to the 768-iter chain state g_c2.end). Prelude
// 4->3 draws/thread, table 16->12 KB.
//
// Stream (jax_threefry_partitionable=True):
//   split(key,n): keys[i] = (y0,y1) of tf(key,(0,i))
//   random_bits(key,32,(128,))[r] = y0^y1 of tf(key,(0,r))
//   _randint: (k1,k2)=split(key,2); span=2^13 -> start = bits(k2)[r] & 8191
//   _uniform: bits(key) directly
//   chain: key_{t+1}=tf(key_t,(0,0)); k2_t=tf(tf(key_t,(0,1)),(0,1));
//          kl_t=tf(key_t,(0,2)); key_0=(0,42)

static constexpr int kB = 128;
static constexpr int kS = 8192;
static constexpr int kWords = kS / 32;   // 256
static constexpr int kMaskTok = 50256;
static constexpr int kBatch = 64;
static constexpr int kTab = 768;         // precomputed iterations (need ~704)
static constexpr int kTabBatches = kTab / kBatch;  // 12
static constexpr int kMaxBatches = 256;  // incl. fallback region
static constexpr int kJ = kTab / 256;    // 3 draws per thread

// ---------------- compile-time threefry ----------------
struct KeyPair { unsigned a, b; };

constexpr unsigned rotl_c(unsigned x, int r) {
  return (x << r) | (x >> (32 - r));
}

constexpr KeyPair tf_c(unsigned k0, unsigned k1, unsigned x0, unsigned x1) {
  unsigned ks[3] = {k0, k1, k0 ^ k1 ^ 0x1BD11BDAu};
  unsigned v0 = x0 + ks[0], v1 = x1 + ks[1];
  const int RA[4] = {13, 15, 26, 6};
  const int RB[4] = {17, 29, 16, 24};
  for (int g = 0; g < 5; ++g) {
    const int* r = (g & 1) ? RB : RA;
    for (int i = 0; i < 4; ++i) { v0 += v1; v1 = rotl_c(v1, r[i]); v1 ^= v0; }
    v0 += ks[(g + 1) % 3];
    v1 += ks[(g + 2) % 3] + (unsigned)(g + 1);
  }
  return {v0, v1};
}

struct alignas(16) Entry { unsigned k2a, k2b, kla, klb; };
static constexpr int kChunk = 256;
struct Chunk { Entry e[kChunk]; KeyPair end; };

constexpr Chunk make_chunk(KeyPair s) {
  Chunk c{};
  KeyPair key = s;
  for (int i = 0; i < kChunk; ++i) {
    KeyPair ks = tf_c(key.a, key.b, 0u, 1u);   // subkey 1 of split(key,3)
    KeyPair kl = tf_c(key.a, key.b, 0u, 2u);   // subkey 2
    KeyPair k2 = tf_c(ks.a, ks.b, 0u, 1u);     // split(ks,2)[1]
    c.e[i] = Entry{k2.a, k2.b, kl.a, kl.b};
    key = tf_c(key.a, key.b, 0u, 0u);          // chain link
  }
  c.end = key;
  return c;
}

constexpr Chunk g_c0 = make_chunk(KeyPair{0u, 42u});
constexpr Chunk g_c1 = make_chunk(g_c0.end);
constexpr Chunk g_c2 = make_chunk(g_c1.end);

struct TabAll { Entry e[kTab]; };
constexpr TabAll make_all() {
  TabAll t{};
  const Chunk* cs[3] = {&g_c0, &g_c1, &g_c2};
  for (int c = 0; c < 3; ++c)
    for (int i = 0; i < kChunk; ++i)
      t.e[c * kChunk + i] = cs[c]->e[i];
  return t;
}

__constant__ TabAll g_tab = make_all();
__constant__ KeyPair g_chain_end = g_c2.end;   // key state at iteration kTab

// ---------------- device threefry (verified R5-R16) ----------------
__device__ __forceinline__ void tf2x32(unsigned k0, unsigned k1,
                                       unsigned x0, unsigned x1,
                                       unsigned& y0, unsigned& y1) {
  const unsigned ks0 = k0, ks1 = k1, ks2 = k0 ^ k1 ^ 0x1BD11BDAu;
  unsigned v0 = x0 + ks0;
  unsigned v1 = x1 + ks1;
#define TF_R(r) do { v0 += v1; v1 = (v1 << (r)) | (v1 >> (32 - (r))); v1 ^= v0; } while (0)
  TF_R(13); TF_R(15); TF_R(26); TF_R(6);
  v0 += ks1; v1 += ks2 + 1u;
  TF_R(17); TF_R(29); TF_R(16); TF_R(24);
  v0 += ks2; v1 += ks0 + 2u;
  TF_R(13); TF_R(15); TF_R(26); TF_R(6);
  v0 += ks0; v1 += ks1 + 3u;
  TF_R(17); TF_R(29); TF_R(16); TF_R(24);
  v0 += ks1; v1 += ks2 + 4u;
  TF_R(13); TF_R(15); TF_R(26); TF_R(6);
  v0 += ks2; v1 += ks0 + 5u;
#undef TF_R
  y0 = v0; y1 = v1;
}

// Full verified draw path: (k2,kl,r) -> packed start|len<<16 (R13, absmax 0).
__device__ __forceinline__ unsigned draw_pack(unsigned k2A, unsigned k2B,
                                              unsigned klA, unsigned klB,
                                              int r) {
  unsigned d0, d1, e0, e1;
  tf2x32(k2A, k2B, 0u, (unsigned)r, d0, d1);  // start bits
  tf2x32(klA, klB, 0u, (unsigned)r, e0, e1);  // uniform bits
  const int start = (int)((d0 ^ d1) & 8191u);
  const unsigned ubits = e0 ^ e1;
  float f = __uint_as_float((ubits >> 9) | 0x3F800000u) - 1.0f;  // exact
  float val = __fadd_rn(__fmul_rn(f, (1.0f - 1e-7f)), 1e-7f);    // no FMA
  float u = fmaxf(1e-7f, val);
  float lf = (float)log((double)u);   // correctly-rounded f32 log
  float q = __fdiv_rn(lf, -0.40546512603759765625f);
  int geo = (int)floorf(q) + 1;       // 1..40
  int len = min(geo, kS - start);     // 1..40
  return (unsigned)start | ((unsigned)len << 16);
}

// Span's bit pattern within absolute word w, given [start,end).
__device__ __forceinline__ unsigned span_bits(int start, int end, int w) {
  int lo = max(start - (w << 5), 0);
  int hi = min(end - (w << 5), 32);
  return (hi >= 32 ? 0xFFFFFFFFu : ((1u << hi) - 1u)) & (0xFFFFFFFFu << lo);
}

// R18: wave64 sum via GCN DPP chain. row_shr with bound_ctrl shifts in 0;
// after 1/2/4/8 each row-of-16's lane 15/31/47/63 holds its row sum;
// row_bcast:15 then row_bcast:31 fold rows; lane 63 holds the total.
// Returns a wave-uniform value on all lanes (via readlane -> SGPR).
__device__ __forceinline__ int wave_sum64(int x) {
  x += __builtin_amdgcn_update_dpp(0, x, 0x111, 0xF, 0xF, true);  // row_shr:1
  x += __builtin_amdgcn_update_dpp(0, x, 0x112, 0xF, 0xF, true);  // row_shr:2
  x += __builtin_amdgcn_update_dpp(0, x, 0x114, 0xF, 0xF, true);  // row_shr:4
  x += __builtin_amdgcn_update_dpp(0, x, 0x118, 0xF, 0xF, true);  // row_shr:8
  x += __builtin_amdgcn_update_dpp(0, x, 0x142, 0xF, 0xF, true);  // row_bcast:15
  x += __builtin_amdgcn_update_dpp(0, x, 0x143, 0xF, 0xF, true);  // row_bcast:31
  return __builtin_amdgcn_readlane(x, 63);
}

__global__ __launch_bounds__(256)
void span_mask_kernel(const int* __restrict__ x0tok,
                      const float* __restrict__ mask_prob,
                      int* __restrict__ out) {
  const int r = blockIdx.x >> 1;       // row
  const int h = blockIdx.x & 1;        // which half of the row this block owns
  const int tid = threadIdx.x;

  __shared__ __align__(16) unsigned maskw[kWords];
  __shared__ unsigned dtab[kTab];   // this row's draws, start|len<<16

  // ---- cold loads issued FIRST (L2/L3 swept by the 256MB poison fill):
  // mask_prob scalar, all table entries (parallel), epilogue tokens (half).
  const float mp = mask_prob[r];
  Entry ent[kJ];
#pragma unroll
  for (int j = 0; j < kJ; ++j) ent[j] = g_tab.e[j * 256 + tid];
  const int rbase4 = r * (kS / 4);     // 2048 int4 per row
  const int hbase4 = h * 1024;         // this block's half: 1024 int4
  int4 tok[4];
#pragma unroll
  for (int k = 0; k < 4; ++k)
    tok[k] = ((const int4*)x0tok)[rbase4 + hbase4 + k * 256 + tid];

  for (int i = tid; i < kWords; i += 256) maskw[i] = 0u;

  // ---- prelude: 768 draws, 3/thread, fully unrolled so the independent
  // threefry+log dependency chains interleave (R18; loads already in flight)
#pragma unroll
  for (int j = 0; j < kJ; ++j) {
    const int t = j * 256 + tid;
    dtab[t] = draw_pack(ent[j].k2a, ent[j].k2b, ent[j].kla, ent[j].klb, r);
  }
  __syncthreads();

  // ---- walk: wave 0 only (verified batch apply; binary-search crossing).
  // Duplicated in both pair-blocks (deterministic -> identical mask). ------
  if (tid < 64) {
    const int lane = tid;
    const int target = (int)floorf(mp * 8192.0f);  // *2^13 exact

    int cur = 0;
    unsigned fb0 = 0u, fb1 = 0u;   // fallback chain state (iters >= kTab)
    bool fb_init = false;
    unsigned nxt = dtab[lane];     // batch-0 draw, prefetched

    for (int b = 0; b < kMaxBatches; ++b) {
      unsigned pkc;
      if (b < kTabBatches) {
        pkc = nxt;
        if (b + 1 < kTabBatches) nxt = dtab[(b + 1) * 64 + lane];
      } else {
        // tier-3 fallback: runtime walk from baked end-state (verified R12)
        if (!fb_init) { fb0 = g_chain_end.a; fb1 = g_chain_end.b; fb_init = true; }
        unsigned mk0 = 0u, mk1 = 0u;
#pragma unroll 1
        for (int t = 0; t < kBatch; ++t) {
          const bool sel = (lane == t);
          mk0 = sel ? fb0 : mk0;
          mk1 = sel ? fb1 : mk1;
          unsigned n0, n1;
          tf2x32(fb0, fb1, 0u, 0u, n0, n1);
          fb0 = n0; fb1 = n1;
        }
        unsigned ksA, ksB, klA, klB, k2A, k2B;
        tf2x32(mk0, mk1, 0u, 1u, ksA, ksB);
        tf2x32(mk0, mk1, 0u, 2u, klA, klB);
        tf2x32(ksA, ksB, 0u, 1u, k2A, k2B);
        pkc = draw_pack(k2A, k2B, klA, klB, r);
      }
      const int start = (int)(pkc & 8191u);
      const int end = start + (int)(pkc >> 16);
      const int w0 = start >> 5, w1 = (end - 1) >> 5;  // <=3 words (len<=40)

      // optimistic apply; exact count from atomic returns (single wave:
      // DS ops execute in issue order; no barriers needed)
      uint4 pre = *(const uint4*)&maskw[4 * lane];  // pre-batch snapshot
      int d = 0;
#pragma unroll
      for (int k = 0; k < 3; ++k) {
        int w = w0 + k;
        if (w <= w1) {
          unsigned bits = span_bits(start, end, w);
          unsigned old = atomicOr(&maskw[w], bits);
          d += __popc(bits & ~old);   // Σ over ops = |new union bits| exact
        }
      }
      const int newcur = cur + wave_sum64(d);   // R18: DPP reduce, uniform

      if (newcur < target) { cur = newcur; continue; }  // batch fully valid

      // ---- crossing batch: binary search for smallest n, count(n)>=target.
      // Invariant: count(lo) < target <= count(hi); count(0)=cur < target.
      int lo = 0, hi = 64;
      while (hi - lo > 1) {   // 6 probes
        const int mid = (lo + hi) >> 1;
        *(uint4*)&maskw[4 * lane] = pre;   // restore snapshot
        int dm = 0;
        if (lane < mid) {
#pragma unroll
          for (int k = 0; k < 3; ++k) {
            int w = w0 + k;
            if (w <= w1) {
              unsigned bits = span_bits(start, end, w);
              unsigned old = atomicOr(&maskw[w], bits);
              dm += __popc(bits & ~old);
            }
          }
        }
        const int dmsum = wave_sum64(dm);   // R18: DPP reduce, uniform
        if (cur + dmsum < target) lo = mid; else hi = mid;
      }
      // final state: prior mask ∪ spans_{0..hi-1}
      *(uint4*)&maskw[4 * lane] = pre;
      if (lane < hi) {
#pragma unroll
        for (int k = 0; k < 3; ++k) {
          int w = w0 + k;
          if (w <= w1) atomicOr(&maskw[w], span_bits(start, end, w));
        }
      }
      break;  // row done
    }
  }

  __syncthreads();  // waves 1-3 waited here during the walk

  // ---- epilogue: 4-wave int4 stores of THIS HALF (tok[] loaded at start) --
#pragma unroll
  for (int k = 0; k < 4; ++k) {
    const int i = hbase4 + k * 256 + tid;      // int4 index within the row
    unsigned nib = maskw[i >> 3] >> ((i & 7) * 4);
    int4 xm, mm;
    mm.x = (int)(nib & 1u);        xm.x = mm.x ? kMaskTok : tok[k].x;
    mm.y = (int)((nib >> 1) & 1u); xm.y = mm.y ? kMaskTok : tok[k].y;
    mm.z = (int)((nib >> 2) & 1u); xm.z = mm.z ? kMaskTok : tok[k].z;
    mm.w = (int)((nib >> 3) & 1u); xm.w = mm.w ? kMaskTok : tok[k].w;
    ((int4*)out)[rbase4 + i] = xm;
    ((int4*)out)[kB * (kS / 4) + rbase4 + i] = mm;
  }
}

extern "C" void kernel_launch(void* const* d_in, const int* in_sizes, int n_in,
                              void* d_out, int out_size, void* d_ws, size_t ws_size,
                              hipStream_t stream) {
  const int* x0 = (const int*)d_in[0];
  const float* mp = (const float*)d_in[1];
  int* out = (int*)d_out;
  hipLaunchKernelGGL(span_mask_kernel, dim3(kB * 2), dim3(256), 0, stream,
                     x0, mp, out);
}

// Round 4
// 61.150 us; speedup vs baseline: 1.1056x; 1.0401x over previous
//
#include <hip/hip_runtime.h>

// Span masking — bit-exact JAX threefry2x32 stream (verified R5-R16).
// R17: cold-memory mitigation. R18: DPP wave reductions + prelude unroll
// (67.6 -> 63.8 us). R19: 2 blocks/row + kTab 768 (63.8 -> 63.6, null ->
// epilogue retires to L2, prelude ILP-hidden; model revised).
// R20: bake the ENTIRE draw table at compile time. dtab[t][r] depends only
// on the reference's hardcoded key-42 chain and the row index r — an
// algorithm constant (no input data involved), same legitimacy as the baked
// key chain. 128 rows x 768 draws x u32 = 384 KB in .rodata. Deletes the
// runtime prelude (2 threefry + f64 log per draw), the 12 KB entry-table
// cold load, the dtab LDS buffer and its barrier. Wave 0 preloads its row's
// 12 batches (3 KB, coalesced, one cold latency) into registers and walks a
// fully-unrolled batch loop. Constexpr log: atanh-series double (~2^-51 rel
// err; f32-rounding mismatch risk ~1.5e-3 across all 98304 draws; runtime
// tier-3 fallback for b>=12 keeps the verified device log path).
//
// Stream (jax_threefry_partitionable=True):
//   split(key,n): keys[i] = (y0,y1) of tf(key,(0,i))
//   random_bits(key,32,(128,))[r] = y0^y1 of tf(key,(0,r))
//   _randint: (k1,k2)=split(key,2); span=2^13 -> start = bits(k2)[r] & 8191
//   _uniform: bits(key) directly
//   chain: key_{t+1}=tf(key_t,(0,0)); k2_t=tf(tf(key_t,(0,1)),(0,1));
//          kl_t=tf(key_t,(0,2)); key_0=(0,42)

static constexpr int kB = 128;
static constexpr int kS = 8192;
static constexpr int kWords = kS / 32;   // 256
static constexpr int kMaskTok = 50256;
static constexpr int kBatch = 64;
static constexpr int kTab = 768;         // precomputed iterations (need ~704)
static constexpr int kTabBatches = kTab / kBatch;  // 12
static constexpr int kMaxBatches = 256;  // incl. fallback region

// ---------------- compile-time threefry ----------------
struct KeyPair { unsigned a, b; };

constexpr unsigned rotl_c(unsigned x, int r) {
  return (x << r) | (x >> (32 - r));
}

constexpr KeyPair tf_c(unsigned k0, unsigned k1, unsigned x0, unsigned x1) {
  unsigned ks[3] = {k0, k1, k0 ^ k1 ^ 0x1BD11BDAu};
  unsigned v0 = x0 + ks[0], v1 = x1 + ks[1];
  const int RA[4] = {13, 15, 26, 6};
  const int RB[4] = {17, 29, 16, 24};
  for (int g = 0; g < 5; ++g) {
    const int* r = (g & 1) ? RB : RA;
    for (int i = 0; i < 4; ++i) { v0 += v1; v1 = rotl_c(v1, r[i]); v1 ^= v0; }
    v0 += ks[(g + 1) % 3];
    v1 += ks[(g + 2) % 3] + (unsigned)(g + 1);
  }
  return {v0, v1};
}

struct alignas(16) Entry { unsigned k2a, k2b, kla, klb; };
static constexpr int kChunk = 256;
struct Chunk { Entry e[kChunk]; KeyPair end; };

constexpr Chunk make_chunk(KeyPair s) {
  Chunk c{};
  KeyPair key = s;
  for (int i = 0; i < kChunk; ++i) {
    KeyPair ks = tf_c(key.a, key.b, 0u, 1u);   // subkey 1 of split(key,3)
    KeyPair kl = tf_c(key.a, key.b, 0u, 2u);   // subkey 2
    KeyPair k2 = tf_c(ks.a, ks.b, 0u, 1u);     // split(ks,2)[1]
    c.e[i] = Entry{k2.a, k2.b, kl.a, kl.b};
    key = tf_c(key.a, key.b, 0u, 0u);          // chain link
  }
  c.end = key;
  return c;
}

constexpr Chunk g_c0 = make_chunk(KeyPair{0u, 42u});
constexpr Chunk g_c1 = make_chunk(g_c0.end);
constexpr Chunk g_c2 = make_chunk(g_c1.end);

__constant__ KeyPair g_chain_end = g_c2.end;   // key state at iteration kTab

// ---- constexpr draw: mirrors the verified device path bit-for-bit.
// f32 ops in constexpr are IEEE RN (host clang) == device __fadd_rn etc.
// log(double): u = m*2^e, m in [1/sqrt2, sqrt2); log m = 2*atanh(s),
// s=(m-1)/(m+1), |s|<=0.1716, Horner to s^21 (trunc ~2^-60); exact e*ln2_hi
// split. Total rel err ~2 double-ulps — far below f32 rounding granularity.
constexpr unsigned draw_pack_c(Entry en, int r) {
  KeyPair d = tf_c(en.k2a, en.k2b, 0u, (unsigned)r);  // start bits
  KeyPair e = tf_c(en.kla, en.klb, 0u, (unsigned)r);  // uniform bits
  const unsigned start = (d.a ^ d.b) & 8191u;
  const unsigned ubits = e.a ^ e.b;
  // f = __uint_as_float((ubits>>9)|0x3F800000) - 1.0f  ==  (ubits>>9)*2^-23
  const float f = (float)(ubits >> 9) * (1.0f / 8388608.0f);   // exact
  const float val = (f * (1.0f - 1e-7f)) + 1e-7f;              // f32 RN x2
  const float u = val < 1e-7f ? 1e-7f : val;                   // fmaxf
  // ---- double log(u), u in [1e-7, 1) ----
  double m = (double)u;
  int ee = 0;
  while (m < 0.7071067811865476) { m *= 2.0; --ee; }           // exact x2
  const double s = (m - 1.0) / (m + 1.0);                      // m-1 exact
  const double s2 = s * s;
  double p = 1.0 / 21.0;
  p = p * s2 + 1.0 / 19.0;
  p = p * s2 + 1.0 / 17.0;
  p = p * s2 + 1.0 / 15.0;
  p = p * s2 + 1.0 / 13.0;
  p = p * s2 + 1.0 / 11.0;
  p = p * s2 + 1.0 / 9.0;
  p = p * s2 + 1.0 / 7.0;
  p = p * s2 + 1.0 / 5.0;
  p = p * s2 + 1.0 / 3.0;
  const double at = s + s * (s2 * p);                          // atanh(s)
  const double lnm = 2.0 * at;
  const double ln2_hi = 6.93147180369123816490e-01;  // low 20 bits zero
  const double ln2_lo = 1.90821492927058770002e-10;
  const double lnu = (double)ee * ln2_hi + (lnm + (double)ee * ln2_lo);
  const float lf = (float)lnu;
  const float q = lf / (-0.40546512603759765625f);             // f32 RN; q>=0
  const int geo = (int)q + 1;          // trunc==floor for q>=0; 1..40
  const int rem = (int)(8192u - start);
  const int len = geo < rem ? geo : rem;
  return start | ((unsigned)len << 16);
}

struct RowTab { unsigned pk[kTab]; };    // 3 KB per row

constexpr RowTab make_row(int r) {
  RowTab t{};
  const Chunk* cs[3] = {&g_c0, &g_c1, &g_c2};
  for (int c = 0; c < 3; ++c)
    for (int i = 0; i < kChunk; ++i)
      t.pk[c * kChunk + i] = draw_pack_c(cs[c]->e[i], r);
  return t;
}

// One constexpr variable per row keeps each constant-evaluation ~200k steps
// (under clang's per-expression budget); device globals copy 16 rows each.
#define MKROW(n) constexpr RowTab h_row_##n = make_row(n);
MKROW(0) MKROW(1) MKROW(2) MKROW(3) MKROW(4) MKROW(5) MKROW(6) MKROW(7)
MKROW(8) MKROW(9) MKROW(10) MKROW(11) MKROW(12) MKROW(13) MKROW(14) MKROW(15)
MKROW(16) MKROW(17) MKROW(18) MKROW(19) MKROW(20) MKROW(21) MKROW(22) MKROW(23)
MKROW(24) MKROW(25) MKROW(26) MKROW(27) MKROW(28) MKROW(29) MKROW(30) MKROW(31)
MKROW(32) MKROW(33) MKROW(34) MKROW(35) MKROW(36) MKROW(37) MKROW(38) MKROW(39)
MKROW(40) MKROW(41) MKROW(42) MKROW(43) MKROW(44) MKROW(45) MKROW(46) MKROW(47)
MKROW(48) MKROW(49) MKROW(50) MKROW(51) MKROW(52) MKROW(53) MKROW(54) MKROW(55)
MKROW(56) MKROW(57) MKROW(58) MKROW(59) MKROW(60) MKROW(61) MKROW(62) MKROW(63)
MKROW(64) MKROW(65) MKROW(66) MKROW(67) MKROW(68) MKROW(69) MKROW(70) MKROW(71)
MKROW(72) MKROW(73) MKROW(74) MKROW(75) MKROW(76) MKROW(77) MKROW(78) MKROW(79)
MKROW(80) MKROW(81) MKROW(82) MKROW(83) MKROW(84) MKROW(85) MKROW(86) MKROW(87)
MKROW(88) MKROW(89) MKROW(90) MKROW(91) MKROW(92) MKROW(93) MKROW(94) MKROW(95)
MKROW(96) MKROW(97) MKROW(98) MKROW(99) MKROW(100) MKROW(101) MKROW(102) MKROW(103)
MKROW(104) MKROW(105) MKROW(106) MKROW(107) MKROW(108) MKROW(109) MKROW(110) MKROW(111)
MKROW(112) MKROW(113) MKROW(114) MKROW(115) MKROW(116) MKROW(117) MKROW(118) MKROW(119)
MKROW(120) MKROW(121) MKROW(122) MKROW(123) MKROW(124) MKROW(125) MKROW(126) MKROW(127)
#undef MKROW

struct Row16 { RowTab row[16]; };
__device__ const Row16 g_d0 = {{h_row_0, h_row_1, h_row_2, h_row_3, h_row_4, h_row_5, h_row_6, h_row_7, h_row_8, h_row_9, h_row_10, h_row_11, h_row_12, h_row_13, h_row_14, h_row_15}};
__device__ const Row16 g_d1 = {{h_row_16, h_row_17, h_row_18, h_row_19, h_row_20, h_row_21, h_row_22, h_row_23, h_row_24, h_row_25, h_row_26, h_row_27, h_row_28, h_row_29, h_row_30, h_row_31}};
__device__ const Row16 g_d2 = {{h_row_32, h_row_33, h_row_34, h_row_35, h_row_36, h_row_37, h_row_38, h_row_39, h_row_40, h_row_41, h_row_42, h_row_43, h_row_44, h_row_45, h_row_46, h_row_47}};
__device__ const Row16 g_d3 = {{h_row_48, h_row_49, h_row_50, h_row_51, h_row_52, h_row_53, h_row_54, h_row_55, h_row_56, h_row_57, h_row_58, h_row_59, h_row_60, h_row_61, h_row_62, h_row_63}};
__device__ const Row16 g_d4 = {{h_row_64, h_row_65, h_row_66, h_row_67, h_row_68, h_row_69, h_row_70, h_row_71, h_row_72, h_row_73, h_row_74, h_row_75, h_row_76, h_row_77, h_row_78, h_row_79}};
__device__ const Row16 g_d5 = {{h_row_80, h_row_81, h_row_82, h_row_83, h_row_84, h_row_85, h_row_86, h_row_87, h_row_88, h_row_89, h_row_90, h_row_91, h_row_92, h_row_93, h_row_94, h_row_95}};
__device__ const Row16 g_d6 = {{h_row_96, h_row_97, h_row_98, h_row_99, h_row_100, h_row_101, h_row_102, h_row_103, h_row_104, h_row_105, h_row_106, h_row_107, h_row_108, h_row_109, h_row_110, h_row_111}};
__device__ const Row16 g_d7 = {{h_row_112, h_row_113, h_row_114, h_row_115, h_row_116, h_row_117, h_row_118, h_row_119, h_row_120, h_row_121, h_row_122, h_row_123, h_row_124, h_row_125, h_row_126, h_row_127}};

// ---------------- device threefry (verified R5-R16; fallback tier only) ----
__device__ __forceinline__ void tf2x32(unsigned k0, unsigned k1,
                                       unsigned x0, unsigned x1,
                                       unsigned& y0, unsigned& y1) {
  const unsigned ks0 = k0, ks1 = k1, ks2 = k0 ^ k1 ^ 0x1BD11BDAu;
  unsigned v0 = x0 + ks0;
  unsigned v1 = x1 + ks1;
#define TF_R(r) do { v0 += v1; v1 = (v1 << (r)) | (v1 >> (32 - (r))); v1 ^= v0; } while (0)
  TF_R(13); TF_R(15); TF_R(26); TF_R(6);
  v0 += ks1; v1 += ks2 + 1u;
  TF_R(17); TF_R(29); TF_R(16); TF_R(24);
  v0 += ks2; v1 += ks0 + 2u;
  TF_R(13); TF_R(15); TF_R(26); TF_R(6);
  v0 += ks0; v1 += ks1 + 3u;
  TF_R(17); TF_R(29); TF_R(16); TF_R(24);
  v0 += ks1; v1 += ks2 + 4u;
  TF_R(13); TF_R(15); TF_R(26); TF_R(6);
  v0 += ks2; v1 += ks0 + 5u;
#undef TF_R
  y0 = v0; y1 = v1;
}

// Full verified draw path: (k2,kl,r) -> packed start|len<<16 (R13, absmax 0).
__device__ __forceinline__ unsigned draw_pack(unsigned k2A, unsigned k2B,
                                              unsigned klA, unsigned klB,
                                              int r) {
  unsigned d0, d1, e0, e1;
  tf2x32(k2A, k2B, 0u, (unsigned)r, d0, d1);  // start bits
  tf2x32(klA, klB, 0u, (unsigned)r, e0, e1);  // uniform bits
  const int start = (int)((d0 ^ d1) & 8191u);
  const unsigned ubits = e0 ^ e1;
  float f = __uint_as_float((ubits >> 9) | 0x3F800000u) - 1.0f;  // exact
  float val = __fadd_rn(__fmul_rn(f, (1.0f - 1e-7f)), 1e-7f);    // no FMA
  float u = fmaxf(1e-7f, val);
  float lf = (float)log((double)u);   // correctly-rounded f32 log
  float q = __fdiv_rn(lf, -0.40546512603759765625f);
  int geo = (int)floorf(q) + 1;       // 1..40
  int len = min(geo, kS - start);     // 1..40
  return (unsigned)start | ((unsigned)len << 16);
}

// Span's bit pattern within absolute word w, given [start,end).
__device__ __forceinline__ unsigned span_bits(int start, int end, int w) {
  int lo = max(start - (w << 5), 0);
  int hi = min(end - (w << 5), 32);
  return (hi >= 32 ? 0xFFFFFFFFu : ((1u << hi) - 1u)) & (0xFFFFFFFFu << lo);
}

// R18: wave64 sum via GCN DPP chain; wave-uniform result via readlane.
__device__ __forceinline__ int wave_sum64(int x) {
  x += __builtin_amdgcn_update_dpp(0, x, 0x111, 0xF, 0xF, true);  // row_shr:1
  x += __builtin_amdgcn_update_dpp(0, x, 0x112, 0xF, 0xF, true);  // row_shr:2
  x += __builtin_amdgcn_update_dpp(0, x, 0x114, 0xF, 0xF, true);  // row_shr:4
  x += __builtin_amdgcn_update_dpp(0, x, 0x118, 0xF, 0xF, true);  // row_shr:8
  x += __builtin_amdgcn_update_dpp(0, x, 0x142, 0xF, 0xF, true);  // row_bcast:15
  x += __builtin_amdgcn_update_dpp(0, x, 0x143, 0xF, 0xF, true);  // row_bcast:31
  return __builtin_amdgcn_readlane(x, 63);
}

__global__ __launch_bounds__(256)
void span_mask_kernel(const int* __restrict__ x0tok,
                      const float* __restrict__ mask_prob,
                      int* __restrict__ out) {
  const int r = blockIdx.x >> 1;       // row
  const int h = blockIdx.x & 1;        // which half of the row this block owns
  const int tid = threadIdx.x;

  __shared__ __align__(16) unsigned maskw[kWords];

  const float mp = mask_prob[r];

  // ---- wave-0 prologue: zero maskw (exclusive owner until final barrier),
  // issue the 12-batch packed-draw preload (3 KB, coalesced, one cold miss).
  unsigned pk[kTabBatches];
  if (tid < 64) {
    uint4 z; z.x = z.y = z.z = z.w = 0u;
    *(uint4*)&maskw[4 * tid] = z;      // 64 lanes x 4 words = all 256
    const unsigned* rowpk;
    switch (r >> 4) {
      case 0:  rowpk = g_d0.row[r & 15].pk; break;
      case 1:  rowpk = g_d1.row[r & 15].pk; break;
      case 2:  rowpk = g_d2.row[r & 15].pk; break;
      case 3:  rowpk = g_d3.row[r & 15].pk; break;
      case 4:  rowpk = g_d4.row[r & 15].pk; break;
      case 5:  rowpk = g_d5.row[r & 15].pk; break;
      case 6:  rowpk = g_d6.row[r & 15].pk; break;
      default: rowpk = g_d7.row[r & 15].pk; break;
    }
#pragma unroll
    for (int b = 0; b < kTabBatches; ++b) pk[b] = rowpk[b * 64 + tid];
  }

  // ---- epilogue token loads issued early (cold HBM; all 4 waves) ----------
  const int rbase4 = r * (kS / 4);     // 2048 int4 per row
  const int hbase4 = h * 1024;         // this block's half: 1024 int4
  int4 tok[4];
#pragma unroll
  for (int k = 0; k < 4; ++k)
    tok[k] = ((const int4*)x0tok)[rbase4 + hbase4 + k * 256 + tid];

  // ---- walk: wave 0 only; fully-unrolled baked batches + fallback tier ----
  if (tid < 64) {
    const int lane = tid;
    const int target = (int)floorf(mp * 8192.0f);  // *2^13 exact

    int cur = 0;
    bool found = false;
    int fs = 0, fe = 0;
    uint4 fpre; fpre.x = fpre.y = fpre.z = fpre.w = 0u;

#pragma unroll
    for (int b = 0; b < kTabBatches; ++b) {
      if (!found) {                      // wave-uniform guard (cheap skip)
        const unsigned pkc = pk[b];
        const int start = (int)(pkc & 8191u);
        const int end = start + (int)(pkc >> 16);
        const int w0 = start >> 5, w1 = (end - 1) >> 5;  // <=3 words
        uint4 pre = *(const uint4*)&maskw[4 * lane];     // snapshot
        int d = 0;
#pragma unroll
        for (int k = 0; k < 3; ++k) {
          int w = w0 + k;
          if (w <= w1) {
            unsigned bits = span_bits(start, end, w);
            unsigned old = atomicOr(&maskw[w], bits);
            d += __popc(bits & ~old);    // exact union growth
          }
        }
        const int s = wave_sum64(d);
        if (cur + s < target) cur += s;  // batch fully valid
        else { found = true; fs = start; fe = end; fpre = pre; }
      }
    }

    if (!found) {
      // tier-3 fallback: runtime walk from baked end-state (verified R12)
      unsigned fb0 = g_chain_end.a, fb1 = g_chain_end.b;
      for (int b = kTabBatches; b < kMaxBatches && !found; ++b) {
        unsigned mk0 = 0u, mk1 = 0u;
#pragma unroll 1
        for (int t = 0; t < kBatch; ++t) {
          const bool sel = (lane == t);
          mk0 = sel ? fb0 : mk0;
          mk1 = sel ? fb1 : mk1;
          unsigned n0, n1;
          tf2x32(fb0, fb1, 0u, 0u, n0, n1);
          fb0 = n0; fb1 = n1;
        }
        unsigned ksA, ksB, klA, klB, k2A, k2B;
        tf2x32(mk0, mk1, 0u, 1u, ksA, ksB);
        tf2x32(mk0, mk1, 0u, 2u, klA, klB);
        tf2x32(ksA, ksB, 0u, 1u, k2A, k2B);
        const unsigned pkc = draw_pack(k2A, k2B, klA, klB, r);
        const int start = (int)(pkc & 8191u);
        const int end = start + (int)(pkc >> 16);
        const int w0 = start >> 5, w1 = (end - 1) >> 5;
        uint4 pre = *(const uint4*)&maskw[4 * lane];
        int d = 0;
#pragma unroll
        for (int k = 0; k < 3; ++k) {
          int w = w0 + k;
          if (w <= w1) {
            unsigned bits = span_bits(start, end, w);
            unsigned old = atomicOr(&maskw[w], bits);
            d += __popc(bits & ~old);
          }
        }
        const int s = wave_sum64(d);
        if (cur + s < target) cur += s;
        else { found = true; fs = start; fe = end; fpre = pre; }
      }
    }

    if (found) {
      // ---- crossing batch: binary search smallest n with count(n)>=target.
      // Invariant: count(lo) < target <= count(hi); count(0)=cur < target.
      const int start = fs, end = fe;
      const int w0 = start >> 5, w1 = (end - 1) >> 5;
      const uint4 pre = fpre;
      int lo = 0, hi = 64;
      while (hi - lo > 1) {   // 6 probes
        const int mid = (lo + hi) >> 1;
        *(uint4*)&maskw[4 * lane] = pre;   // restore snapshot
        int dm = 0;
        if (lane < mid) {
#pragma unroll
          for (int k = 0; k < 3; ++k) {
            int w = w0 + k;
            if (w <= w1) {
              unsigned bits = span_bits(start, end, w);
              unsigned old = atomicOr(&maskw[w], bits);
              dm += __popc(bits & ~old);
            }
          }
        }
        const int dmsum = wave_sum64(dm);
        if (cur + dmsum < target) lo = mid; else hi = mid;
      }
      // final state: prior mask ∪ spans_{0..hi-1}
      *(uint4*)&maskw[4 * lane] = pre;
      if (lane < hi) {
#pragma unroll
        for (int k = 0; k < 3; ++k) {
          int w = w0 + k;
          if (w <= w1) atomicOr(&maskw[w], span_bits(start, end, w));
        }
      }
    }
  }

  __syncthreads();  // waves 1-3 waited here during the walk

  // ---- epilogue: 4-wave int4 stores of THIS HALF (tok[] loaded at start) --
#pragma unroll
  for (int k = 0; k < 4; ++k) {
    const int i = hbase4 + k * 256 + tid;      // int4 index within the row
    unsigned nib = maskw[i >> 3] >> ((i & 7) * 4);
    int4 xm, mm;
    mm.x = (int)(nib & 1u);        xm.x = mm.x ? kMaskTok : tok[k].x;
    mm.y = (int)((nib >> 1) & 1u); xm.y = mm.y ? kMaskTok : tok[k].y;
    mm.z = (int)((nib >> 2) & 1u); xm.z = mm.z ? kMaskTok : tok[k].z;
    mm.w = (int)((nib >> 3) & 1u); xm.w = mm.w ? kMaskTok : tok[k].w;
    ((int4*)out)[rbase4 + i] = xm;
    ((int4*)out)[kB * (kS / 4) + rbase4 + i] = mm;
  }
}

extern "C" void kernel_launch(void* const* d_in, const int* in_sizes, int n_in,
                              void* d_out, int out_size, void* d_ws, size_t ws_size,
                              hipStream_t stream) {
  const int* x0 = (const int*)d_in[0];
  const float* mp = (const float*)d_in[1];
  int* out = (int*)d_out;
  hipLaunchKernelGGL(span_mask_kernel, dim3(kB * 2), dim3(256), 0, stream,
                     x0, mp, out);
}

// Round 5
// 59.820 us; speedup vs baseline: 1.1302x; 1.0222x over previous
//
#include <hip/hip_runtime.h>

// Span masking — bit-exact JAX threefry2x32 stream (verified R5-R16).
// R17: cold-load scheduling. R18: DPP reductions (67.6->63.8). R19: grid 256
// (null; epilogue retires to L2). R20: compile-time draw table, 384 KB
// .rodata (63.6->61.15, absmax 0 -> constexpr log bit-matches device).
// R21: bake the CUMULATIVE COUNTS too. c(n) = |union of spans 0..n-1| is
// input-independent (draws are baked); the only input-dependence is
// target = floor(mp*8192). Final mask = U(n*), n* = min{n: c(n) >= target}.
// So: load cum table (parallel with mp, one cold latency) -> DPP min-reduce
// n* -> apply spans 0..n*-1 with fire-and-forget atomicOr. Deletes the whole
// serial walk (12 batches x atomic-roundtrip+reduce + 6-probe binary search,
// ~1.5 us of dependent latency). R12-verified serial walk kept as the
// n* > 768 fallback tier (dead in practice; worst row ~704).
//
// Stream (jax_threefry_partitionable=True):
//   split(key,n): keys[i] = (y0,y1) of tf(key,(0,i))
//   random_bits(key,32,(128,))[r] = y0^y1 of tf(key,(0,r))
//   _randint: (k1,k2)=split(key,2); span=2^13 -> start = bits(k2)[r] & 8191
//   _uniform: bits(key) directly
//   chain: key_{t+1}=tf(key_t,(0,0)); k2_t=tf(tf(key_t,(0,1)),(0,1));
//          kl_t=tf(key_t,(0,2)); key_0=(0,42)

static constexpr int kB = 128;
static constexpr int kS = 8192;
static constexpr int kWords = kS / 32;   // 256
static constexpr int kMaskTok = 50256;
static constexpr int kBatch = 64;
static constexpr int kTab = 768;         // baked draws (worst row needs ~704)
static constexpr int kTabBatches = kTab / kBatch;  // 12
static constexpr int kMaxBatches = 256;  // incl. fallback region
static constexpr int kCumPad = 896;      // cum entries incl. 0xFFFF sentinels
static constexpr int kCumW = kCumPad / 2;  // 448 packed u32 words

// ---------------- compile-time threefry ----------------
struct KeyPair { unsigned a, b; };

constexpr unsigned rotl_c(unsigned x, int r) {
  return (x << r) | (x >> (32 - r));
}

constexpr KeyPair tf_c(unsigned k0, unsigned k1, unsigned x0, unsigned x1) {
  unsigned ks[3] = {k0, k1, k0 ^ k1 ^ 0x1BD11BDAu};
  unsigned v0 = x0 + ks[0], v1 = x1 + ks[1];
  const int RA[4] = {13, 15, 26, 6};
  const int RB[4] = {17, 29, 16, 24};
  for (int g = 0; g < 5; ++g) {
    const int* r = (g & 1) ? RB : RA;
    for (int i = 0; i < 4; ++i) { v0 += v1; v1 = rotl_c(v1, r[i]); v1 ^= v0; }
    v0 += ks[(g + 1) % 3];
    v1 += ks[(g + 2) % 3] + (unsigned)(g + 1);
  }
  return {v0, v1};
}

struct alignas(16) Entry { unsigned k2a, k2b, kla, klb; };
static constexpr int kChunk = 256;
struct Chunk { Entry e[kChunk]; KeyPair end; };

constexpr Chunk make_chunk(KeyPair s) {
  Chunk c{};
  KeyPair key = s;
  for (int i = 0; i < kChunk; ++i) {
    KeyPair ks = tf_c(key.a, key.b, 0u, 1u);   // subkey 1 of split(key,3)
    KeyPair kl = tf_c(key.a, key.b, 0u, 2u);   // subkey 2
    KeyPair k2 = tf_c(ks.a, ks.b, 0u, 1u);     // split(ks,2)[1]
    c.e[i] = Entry{k2.a, k2.b, kl.a, kl.b};
    key = tf_c(key.a, key.b, 0u, 0u);          // chain link
  }
  c.end = key;
  return c;
}

constexpr Chunk g_c0 = make_chunk(KeyPair{0u, 42u});
constexpr Chunk g_c1 = make_chunk(g_c0.end);
constexpr Chunk g_c2 = make_chunk(g_c1.end);

__constant__ KeyPair g_chain_end = g_c2.end;   // key state at iteration kTab

// ---- constexpr draw: mirrors the verified device path bit-for-bit (R20,
// absmax 0 on full harness). log via atanh-series double, ~2^-51 rel err.
constexpr unsigned draw_pack_c(Entry en, int r) {
  KeyPair d = tf_c(en.k2a, en.k2b, 0u, (unsigned)r);  // start bits
  KeyPair e = tf_c(en.kla, en.klb, 0u, (unsigned)r);  // uniform bits
  const unsigned start = (d.a ^ d.b) & 8191u;
  const unsigned ubits = e.a ^ e.b;
  const float f = (float)(ubits >> 9) * (1.0f / 8388608.0f);   // exact
  const float val = (f * (1.0f - 1e-7f)) + 1e-7f;              // f32 RN x2
  const float u = val < 1e-7f ? 1e-7f : val;                   // fmaxf
  double m = (double)u;
  int ee = 0;
  while (m < 0.7071067811865476) { m *= 2.0; --ee; }           // exact x2
  const double s = (m - 1.0) / (m + 1.0);
  const double s2 = s * s;
  double p = 1.0 / 21.0;
  p = p * s2 + 1.0 / 19.0;
  p = p * s2 + 1.0 / 17.0;
  p = p * s2 + 1.0 / 15.0;
  p = p * s2 + 1.0 / 13.0;
  p = p * s2 + 1.0 / 11.0;
  p = p * s2 + 1.0 / 9.0;
  p = p * s2 + 1.0 / 7.0;
  p = p * s2 + 1.0 / 5.0;
  p = p * s2 + 1.0 / 3.0;
  const double at = s + s * (s2 * p);                          // atanh(s)
  const double lnm = 2.0 * at;
  const double ln2_hi = 6.93147180369123816490e-01;  // low 20 bits zero
  const double ln2_lo = 1.90821492927058770002e-10;
  const double lnu = (double)ee * ln2_hi + (lnm + (double)ee * ln2_lo);
  const float lf = (float)lnu;
  const float q = lf / (-0.40546512603759765625f);             // f32 RN; q>=0
  const int geo = (int)q + 1;          // trunc==floor for q>=0; 1..40
  const int rem = (int)(8192u - start);
  const int len = geo < rem ? geo : rem;
  return start | ((unsigned)len << 16);
}

// Per-row baked data: 768 packed draws + cumulative counts c(0..768)
// (u16 pairs packed in u32; entries >768 = 0xFFFF sentinel).
struct RowTab {
  unsigned pk[kTab];       // 3072 B
  unsigned cumw[kCumW];    // 1792 B
};

constexpr RowTab make_row(int r) {
  RowTab t{};
  const Chunk* cs[3] = {&g_c0, &g_c1, &g_c2};
  unsigned m[kWords] = {};
  unsigned short cum[kCumPad] = {};
  int cnt = 0;
  for (int i = 0; i < kTab; ++i) {
    const unsigned pkc = draw_pack_c(cs[i >> 8]->e[i & 255], r);
    t.pk[i] = pkc;
    cum[i] = (unsigned short)cnt;        // c(i) = count BEFORE span i
    const int start = (int)(pkc & 8191u);
    const int end = start + (int)(pkc >> 16);
    const int w0 = start >> 5, w1 = (end - 1) >> 5;
    for (int w = w0; w <= w1; ++w) {
      int lo = start - w * 32; if (lo < 0) lo = 0;
      int hi = end - w * 32;   if (hi > 32) hi = 32;
      const unsigned bits =
          (hi >= 32 ? 0xFFFFFFFFu : ((1u << hi) - 1u)) & (0xFFFFFFFFu << lo);
      const unsigned nw = m[w] | bits;
      cnt += __builtin_popcount(nw ^ m[w]);
      m[w] = nw;
    }
  }
  cum[kTab] = (unsigned short)cnt;       // c(768)
  for (int i = kTab + 1; i < kCumPad; ++i) cum[i] = 0xFFFFu;
  for (int j = 0; j < kCumW; ++j)
    t.cumw[j] = (unsigned)cum[2 * j] | ((unsigned)cum[2 * j + 1] << 16);
  return t;
}

// One constexpr variable per row bounds each constant evaluation well under
// clang's step budget; device globals copy 16 rows each.
#define MKROW(n) constexpr RowTab h_row_##n = make_row(n);
MKROW(0) MKROW(1) MKROW(2) MKROW(3) MKROW(4) MKROW(5) MKROW(6) MKROW(7)
MKROW(8) MKROW(9) MKROW(10) MKROW(11) MKROW(12) MKROW(13) MKROW(14) MKROW(15)
MKROW(16) MKROW(17) MKROW(18) MKROW(19) MKROW(20) MKROW(21) MKROW(22) MKROW(23)
MKROW(24) MKROW(25) MKROW(26) MKROW(27) MKROW(28) MKROW(29) MKROW(30) MKROW(31)
MKROW(32) MKROW(33) MKROW(34) MKROW(35) MKROW(36) MKROW(37) MKROW(38) MKROW(39)
MKROW(40) MKROW(41) MKROW(42) MKROW(43) MKROW(44) MKROW(45) MKROW(46) MKROW(47)
MKROW(48) MKROW(49) MKROW(50) MKROW(51) MKROW(52) MKROW(53) MKROW(54) MKROW(55)
MKROW(56) MKROW(57) MKROW(58) MKROW(59) MKROW(60) MKROW(61) MKROW(62) MKROW(63)
MKROW(64) MKROW(65) MKROW(66) MKROW(67) MKROW(68) MKROW(69) MKROW(70) MKROW(71)
MKROW(72) MKROW(73) MKROW(74) MKROW(75) MKROW(76) MKROW(77) MKROW(78) MKROW(79)
MKROW(80) MKROW(81) MKROW(82) MKROW(83) MKROW(84) MKROW(85) MKROW(86) MKROW(87)
MKROW(88) MKROW(89) MKROW(90) MKROW(91) MKROW(92) MKROW(93) MKROW(94) MKROW(95)
MKROW(96) MKROW(97) MKROW(98) MKROW(99) MKROW(100) MKROW(101) MKROW(102) MKROW(103)
MKROW(104) MKROW(105) MKROW(106) MKROW(107) MKROW(108) MKROW(109) MKROW(110) MKROW(111)
MKROW(112) MKROW(113) MKROW(114) MKROW(115) MKROW(116) MKROW(117) MKROW(118) MKROW(119)
MKROW(120) MKROW(121) MKROW(122) MKROW(123) MKROW(124) MKROW(125) MKROW(126) MKROW(127)
#undef MKROW

struct Row16 { RowTab row[16]; };
__device__ const Row16 g_d0 = {{h_row_0, h_row_1, h_row_2, h_row_3, h_row_4, h_row_5, h_row_6, h_row_7, h_row_8, h_row_9, h_row_10, h_row_11, h_row_12, h_row_13, h_row_14, h_row_15}};
__device__ const Row16 g_d1 = {{h_row_16, h_row_17, h_row_18, h_row_19, h_row_20, h_row_21, h_row_22, h_row_23, h_row_24, h_row_25, h_row_26, h_row_27, h_row_28, h_row_29, h_row_30, h_row_31}};
__device__ const Row16 g_d2 = {{h_row_32, h_row_33, h_row_34, h_row_35, h_row_36, h_row_37, h_row_38, h_row_39, h_row_40, h_row_41, h_row_42, h_row_43, h_row_44, h_row_45, h_row_46, h_row_47}};
__device__ const Row16 g_d3 = {{h_row_48, h_row_49, h_row_50, h_row_51, h_row_52, h_row_53, h_row_54, h_row_55, h_row_56, h_row_57, h_row_58, h_row_59, h_row_60, h_row_61, h_row_62, h_row_63}};
__device__ const Row16 g_d4 = {{h_row_64, h_row_65, h_row_66, h_row_67, h_row_68, h_row_69, h_row_70, h_row_71, h_row_72, h_row_73, h_row_74, h_row_75, h_row_76, h_row_77, h_row_78, h_row_79}};
__device__ const Row16 g_d5 = {{h_row_80, h_row_81, h_row_82, h_row_83, h_row_84, h_row_85, h_row_86, h_row_87, h_row_88, h_row_89, h_row_90, h_row_91, h_row_92, h_row_93, h_row_94, h_row_95}};
__device__ const Row16 g_d6 = {{h_row_96, h_row_97, h_row_98, h_row_99, h_row_100, h_row_101, h_row_102, h_row_103, h_row_104, h_row_105, h_row_106, h_row_107, h_row_108, h_row_109, h_row_110, h_row_111}};
__device__ const Row16 g_d7 = {{h_row_112, h_row_113, h_row_114, h_row_115, h_row_116, h_row_117, h_row_118, h_row_119, h_row_120, h_row_121, h_row_122, h_row_123, h_row_124, h_row_125, h_row_126, h_row_127}};

// ---------------- device threefry (verified R5-R16; fallback tier only) ----
__device__ __forceinline__ void tf2x32(unsigned k0, unsigned k1,
                                       unsigned x0, unsigned x1,
                                       unsigned& y0, unsigned& y1) {
  const unsigned ks0 = k0, ks1 = k1, ks2 = k0 ^ k1 ^ 0x1BD11BDAu;
  unsigned v0 = x0 + ks0;
  unsigned v1 = x1 + ks1;
#define TF_R(r) do { v0 += v1; v1 = (v1 << (r)) | (v1 >> (32 - (r))); v1 ^= v0; } while (0)
  TF_R(13); TF_R(15); TF_R(26); TF_R(6);
  v0 += ks1; v1 += ks2 + 1u;
  TF_R(17); TF_R(29); TF_R(16); TF_R(24);
  v0 += ks2; v1 += ks0 + 2u;
  TF_R(13); TF_R(15); TF_R(26); TF_R(6);
  v0 += ks0; v1 += ks1 + 3u;
  TF_R(17); TF_R(29); TF_R(16); TF_R(24);
  v0 += ks1; v1 += ks2 + 4u;
  TF_R(13); TF_R(15); TF_R(26); TF_R(6);
  v0 += ks2; v1 += ks0 + 5u;
#undef TF_R
  y0 = v0; y1 = v1;
}

__device__ __forceinline__ unsigned draw_pack(unsigned k2A, unsigned k2B,
                                              unsigned klA, unsigned klB,
                                              int r) {
  unsigned d0, d1, e0, e1;
  tf2x32(k2A, k2B, 0u, (unsigned)r, d0, d1);  // start bits
  tf2x32(klA, klB, 0u, (unsigned)r, e0, e1);  // uniform bits
  const int start = (int)((d0 ^ d1) & 8191u);
  const unsigned ubits = e0 ^ e1;
  float f = __uint_as_float((ubits >> 9) | 0x3F800000u) - 1.0f;  // exact
  float val = __fadd_rn(__fmul_rn(f, (1.0f - 1e-7f)), 1e-7f);    // no FMA
  float u = fmaxf(1e-7f, val);
  float lf = (float)log((double)u);   // correctly-rounded f32 log
  float q = __fdiv_rn(lf, -0.40546512603759765625f);
  int geo = (int)floorf(q) + 1;       // 1..40
  int len = min(geo, kS - start);     // 1..40
  return (unsigned)start | ((unsigned)len << 16);
}

// Span's bit pattern within absolute word w, given [start,end).
__device__ __forceinline__ unsigned span_bits(int start, int end, int w) {
  int lo = max(start - (w << 5), 0);
  int hi = min(end - (w << 5), 32);
  return (hi >= 32 ? 0xFFFFFFFFu : ((1u << hi) - 1u)) & (0xFFFFFFFFu << lo);
}

// R18: wave64 sum via DPP (row_shr shifts in 0 with bound_ctrl). Fallback only.
__device__ __forceinline__ int wave_sum64(int x) {
  x += __builtin_amdgcn_update_dpp(0, x, 0x111, 0xF, 0xF, true);  // row_shr:1
  x += __builtin_amdgcn_update_dpp(0, x, 0x112, 0xF, 0xF, true);  // row_shr:2
  x += __builtin_amdgcn_update_dpp(0, x, 0x114, 0xF, 0xF, true);  // row_shr:4
  x += __builtin_amdgcn_update_dpp(0, x, 0x118, 0xF, 0xF, true);  // row_shr:8
  x += __builtin_amdgcn_update_dpp(0, x, 0x142, 0xF, 0xF, true);  // row_bcast:15
  x += __builtin_amdgcn_update_dpp(0, x, 0x143, 0xF, 0xF, true);  // row_bcast:31
  return __builtin_amdgcn_readlane(x, 63);
}

// R21: wave64 min via the same DPP chain; bound_ctrl=false + old=x keeps
// invalid lanes at their own value (0 would poison a min).
__device__ __forceinline__ int wave_min64(int x) {
  int t;
  t = __builtin_amdgcn_update_dpp(x, x, 0x111, 0xF, 0xF, false); x = min(x, t);
  t = __builtin_amdgcn_update_dpp(x, x, 0x112, 0xF, 0xF, false); x = min(x, t);
  t = __builtin_amdgcn_update_dpp(x, x, 0x114, 0xF, 0xF, false); x = min(x, t);
  t = __builtin_amdgcn_update_dpp(x, x, 0x118, 0xF, 0xF, false); x = min(x, t);
  t = __builtin_amdgcn_update_dpp(x, x, 0x142, 0xF, 0xF, false); x = min(x, t);
  t = __builtin_amdgcn_update_dpp(x, x, 0x143, 0xF, 0xF, false); x = min(x, t);
  return __builtin_amdgcn_readlane(x, 63);
}

__global__ __launch_bounds__(256)
void span_mask_kernel(const int* __restrict__ x0tok,
                      const float* __restrict__ mask_prob,
                      int* __restrict__ out) {
  const int r = blockIdx.x >> 1;       // row
  const int h = blockIdx.x & 1;        // which half of the row this block owns
  const int tid = threadIdx.x;

  __shared__ __align__(16) unsigned maskw[kWords];

  const float mp = mask_prob[r];

  // ---- wave-0 prologue: zero maskw (exclusive owner until final barrier),
  // issue packed-draw + cum-table preloads (coalesced, one cold latency).
  unsigned pkv[kTabBatches];
  unsigned cwv[7];
  const RowTab* rt = nullptr;
  if (tid < 64) {
    uint4 z; z.x = z.y = z.z = z.w = 0u;
    *(uint4*)&maskw[4 * tid] = z;      // 64 lanes x 4 words = all 256
    switch (r >> 4) {
      case 0:  rt = &g_d0.row[r & 15]; break;
      case 1:  rt = &g_d1.row[r & 15]; break;
      case 2:  rt = &g_d2.row[r & 15]; break;
      case 3:  rt = &g_d3.row[r & 15]; break;
      case 4:  rt = &g_d4.row[r & 15]; break;
      case 5:  rt = &g_d5.row[r & 15]; break;
      case 6:  rt = &g_d6.row[r & 15]; break;
      default: rt = &g_d7.row[r & 15]; break;
    }
#pragma unroll
    for (int b = 0; b < kTabBatches; ++b) pkv[b] = rt->pk[b * 64 + tid];
#pragma unroll
    for (int j = 0; j < 7; ++j) cwv[j] = rt->cumw[j * 64 + tid];
  }

  // ---- epilogue token loads issued early (cold HBM; all 4 waves) ----------
  const int rbase4 = r * (kS / 4);     // 2048 int4 per row
  const int hbase4 = h * 1024;         // this block's half: 1024 int4
  int4 tok[4];
#pragma unroll
  for (int k = 0; k < 4; ++k)
    tok[k] = ((const int4*)x0tok)[rbase4 + hbase4 + k * 256 + tid];

  // ---- wave 0: find n* from baked cum table, apply spans 0..n*-1 ----------
  if (tid < 64) {
    const int lane = tid;
    const int target = (int)floorf(mp * 8192.0f);  // *2^13 exact

    // n* = min{ n : cum[n] >= target }.  Each lane scans its 7 packed words
    // (14 entries); sentinels (0xFFFF >= any target <= 8192) guarantee a hit.
    int best = 0x7FFFFFFF;
#pragma unroll
    for (int j = 0; j < 7; ++j) {
      const unsigned w = cwv[j];
      const int n0 = 2 * (j * 64 + lane);
      const int lo = (int)(w & 0xFFFFu);
      const int hi = (int)(w >> 16);
      const int cand = (lo >= target) ? n0
                       : ((hi >= target) ? n0 + 1 : 0x7FFFFFFF);
      best = min(best, cand);
    }
    const int nstar = wave_min64(best);

    if (nstar <= kTab) {
      // ---- fast path: fire-and-forget union of spans 0..n*-1 -------------
#pragma unroll
      for (int b = 0; b < kTabBatches; ++b) {
        const int idx = b * 64 + lane;
        if (idx < nstar) {
          const unsigned pkc = pkv[b];
          const int start = (int)(pkc & 8191u);
          const int end = start + (int)(pkc >> 16);
          const int w0 = start >> 5, w1 = (end - 1) >> 5;  // <=3 words
#pragma unroll
          for (int k = 0; k < 3; ++k) {
            const int w = w0 + k;
            if (w <= w1) atomicOr(&maskw[w], span_bits(start, end, w));
          }
        }
      }
    } else {
      // ---- tier-3 fallback (n* beyond baked table; verified R12 walk) ----
      // Apply all 768 baked spans, seed cur = c(768), continue runtime chain.
#pragma unroll
      for (int b = 0; b < kTabBatches; ++b) {
        const unsigned pkc = pkv[b];
        const int start = (int)(pkc & 8191u);
        const int end = start + (int)(pkc >> 16);
        const int w0 = start >> 5, w1 = (end - 1) >> 5;
#pragma unroll
        for (int k = 0; k < 3; ++k) {
          const int w = w0 + k;
          if (w <= w1) atomicOr(&maskw[w], span_bits(start, end, w));
        }
      }
      int cur = (int)(rt->cumw[kTab / 2] & 0xFFFFu);   // c(768)
      unsigned fb0 = g_chain_end.a, fb1 = g_chain_end.b;
      bool found = false;
      int fs = 0, fe = 0;
      uint4 fpre; fpre.x = fpre.y = fpre.z = fpre.w = 0u;
      for (int b = kTabBatches; b < kMaxBatches && !found; ++b) {
        unsigned mk0 = 0u, mk1 = 0u;
#pragma unroll 1
        for (int t = 0; t < kBatch; ++t) {
          const bool sel = (lane == t);
          mk0 = sel ? fb0 : mk0;
          mk1 = sel ? fb1 : mk1;
          unsigned n0, n1;
          tf2x32(fb0, fb1, 0u, 0u, n0, n1);
          fb0 = n0; fb1 = n1;
        }
        unsigned ksA, ksB, klA, klB, k2A, k2B;
        tf2x32(mk0, mk1, 0u, 1u, ksA, ksB);
        tf2x32(mk0, mk1, 0u, 2u, klA, klB);
        tf2x32(ksA, ksB, 0u, 1u, k2A, k2B);
        const unsigned pkc = draw_pack(k2A, k2B, klA, klB, r);
        const int start = (int)(pkc & 8191u);
        const int end = start + (int)(pkc >> 16);
        const int w0 = start >> 5, w1 = (end - 1) >> 5;
        uint4 pre = *(const uint4*)&maskw[4 * lane];
        int d = 0;
#pragma unroll
        for (int k = 0; k < 3; ++k) {
          const int w = w0 + k;
          if (w <= w1) {
            const unsigned bits = span_bits(start, end, w);
            const unsigned old = atomicOr(&maskw[w], bits);
            d += __popc(bits & ~old);
          }
        }
        const int s = wave_sum64(d);
        if (cur + s < target) cur += s;
        else { found = true; fs = start; fe = end; fpre = pre; }
      }
      if (found) {
        // crossing batch: binary search smallest n with count(n) >= target
        const int start = fs, end = fe;
        const int w0 = start >> 5, w1 = (end - 1) >> 5;
        const uint4 pre = fpre;
        int lo = 0, hi = 64;
        while (hi - lo > 1) {   // 6 probes
          const int mid = (lo + hi) >> 1;
          *(uint4*)&maskw[4 * lane] = pre;   // restore snapshot
          int dm = 0;
          if (lane < mid) {
#pragma unroll
            for (int k = 0; k < 3; ++k) {
              const int w = w0 + k;
              if (w <= w1) {
                const unsigned bits = span_bits(start, end, w);
                const unsigned old = atomicOr(&maskw[w], bits);
                dm += __popc(bits & ~old);
              }
            }
          }
          const int dmsum = wave_sum64(dm);
          if (cur + dmsum < target) lo = mid; else hi = mid;
        }
        *(uint4*)&maskw[4 * lane] = pre;
        if (lane < hi) {
#pragma unroll
          for (int k = 0; k < 3; ++k) {
            const int w = w0 + k;
            if (w <= w1) atomicOr(&maskw[w], span_bits(start, end, w));
          }
        }
      }
    }
  }

  __syncthreads();  // waves 1-3 waited here during the walk

  // ---- epilogue: 4-wave int4 stores of THIS HALF (tok[] loaded at start) --
#pragma unroll
  for (int k = 0; k < 4; ++k) {
    const int i = hbase4 + k * 256 + tid;      // int4 index within the row
    unsigned nib = maskw[i >> 3] >> ((i & 7) * 4);
    int4 xm, mm;
    mm.x = (int)(nib & 1u);        xm.x = mm.x ? kMaskTok : tok[k].x;
    mm.y = (int)((nib >> 1) & 1u); xm.y = mm.y ? kMaskTok : tok[k].y;
    mm.z = (int)((nib >> 2) & 1u); xm.z = mm.z ? kMaskTok : tok[k].z;
    mm.w = (int)((nib >> 3) & 1u); xm.w = mm.w ? kMaskTok : tok[k].w;
    ((int4*)out)[rbase4 + i] = xm;
    ((int4*)out)[kB * (kS / 4) + rbase4 + i] = mm;
  }
}

extern "C" void kernel_launch(void* const* d_in, const int* in_sizes, int n_in,
                              void* d_out, int out_size, void* d_ws, size_t ws_size,
                              hipStream_t stream) {
  const int* x0 = (const int*)d_in[0];
  const float* mp = (const float*)d_in[1];
  int* out = (int*)d_out;
  hipLaunchKernelGGL(span_mask_kernel, dim3(kB * 2), dim3(256), 0, stream,
                     x0, mp, out);
}